// Round 12
// baseline (30.913 us; speedup 1.0000x reference)
//
#include <hip/hip_runtime.h>

// Depth-4 path signature, N=64, L=512, C=8. Output/batch:
// [sig1(8) | sig2(64) | sig3(512) | sig4(4096)] = 4680 f32.
//
// R12 = R11 + DIAGNOSTIC dummy phase-A pre-pass (results asm-sunk, order
// pinned). Purpose: dur_delta vs R11 (20.95us) == true phase-A cost, since
// our kernel's counters are hidden behind harness fillBuffer dispatches.
// Output identical to R11; dummy reads a different chunk's LDS window so
// no CSE is possible. Will be reverted next round.

static constexpr int L = 512;
static constexpr int NC = 8;
static constexpr int NSEG = L - 1;                 // 511
static constexpr int SIG = 8 + 64 + 512 + 4096;    // 4680
static constexpr int DXF = NSEG * NC;              // 4088 floats
static constexpr int SLOTOFF = DXF;                // 4088
static constexpr int SLOT = 592;                   // 8 + 64 + 520 (lvl3 stride 65)
static constexpr int CONTRIB = SLOTOFF + 16 * SLOT;  // 13560
static constexpr int TRANSO = CONTRIB + 16 * 1024;   // 29944
static constexpr int LDSF = TRANSO + 64 * 17 + 16;   // 31048 floats
static constexpr size_t LDS_BYTES = (size_t)LDSF * sizeof(float);  // ~121 KB

__device__ __forceinline__ float sel8(float d0, float d1, float d2, float d3,
                                      float d4, float d5, float d6, float d7,
                                      bool b0, bool b1, bool b2) {
    float x0 = b0 ? d1 : d0;
    float x1 = b0 ? d3 : d2;
    float x2 = b0 ? d5 : d4;
    float x3 = b0 ? d7 : d6;
    float y0 = b1 ? x1 : x0;
    float y1 = b1 ? x3 : x2;
    return b2 ? y1 : y0;
}

__global__ __launch_bounds__(1024)
void sig_diag(const float* __restrict__ path, float* __restrict__ out) {
    extern __shared__ __align__(16) float lds[];
    const int tid = threadIdx.x;
    const int w = tid >> 6;          // wave = chunk 0..15
    const int lane = tid & 63;       // (i,j)
    const int i = lane >> 3;
    const int j = lane & 7;
    const int n = blockIdx.x >> 2;   // batch
    const int kq = blockIdx.x & 3;   // k-quarter: k = kq*2, kq*2+1
    const int ka0 = kq * 2, ka1 = ka0 + 1;

    // ---- stage dx into LDS (independent parallel loads) ----
    {
        const float4* pv = reinterpret_cast<const float4*>(path + (size_t)n * (L * NC));
        if (tid < DXF / 4) {  // 1022 float4 diffs
            const float4 a = pv[tid];
            const float4 b = pv[tid + 2];
            *reinterpret_cast<float4*>(&lds[tid * 4]) =
                make_float4(b.x - a.x, b.y - a.y, b.z - a.z, b.w - a.w);
        }
    }
    __syncthreads();

    const bool ib0 = lane & 8, ib1 = lane & 16, ib2 = lane & 32;
    const bool jb0 = lane & 1, jb1 = lane & 2, jb2 = lane & 4;
    const bool kb0 = kq & 1, kb1 = kq & 2;
    constexpr float c3 = 1.f / 6.f;
    constexpr float c4 = 1.f / 24.f;

    // ============ DUMMY phase-A pre-pass (diagnostic; asm-sunk) ==========
    {
        const int seg0d = (w * 32) ^ 256;           // different chunk window
        const float* db = lds + seg0d * 8;
        float t1 = 0.f, t2 = 0.f, t3a = 0.f, t3b = 0.f;
        float ts3[8], taA[8], taB[8];
#pragma unroll
        for (int k = 0; k < 8; ++k) { ts3[k] = 0.f; taA[k] = 0.f; taB[k] = 0.f; }
#pragma unroll 8
        for (int s = 0; s < 32; ++s) {
            const float4 A = *reinterpret_cast<const float4*>(db + s * 8);
            const float4 B = *reinterpret_cast<const float4*>(db + s * 8 + 4);
            const float d0 = A.x, d1 = A.y, d2 = A.z, d3 = A.w;
            const float d4 = B.x, d5 = B.y, d6 = B.z, d7 = B.w;
            const float di = sel8(d0, d1, d2, d3, d4, d5, d6, d7, ib0, ib1, ib2);
            const float dj = sel8(d0, d1, d2, d3, d4, d5, d6, d7, jb0, jb1, jb2);
            const float xa = kb0 ? d2 : d0, xb = kb0 ? d6 : d4;
            const float dk0 = kb1 ? xb : xa;
            const float ya = kb0 ? d3 : d1, yb = kb0 ? d7 : d5;
            const float dk1 = kb1 ? yb : ya;
            const float u = fmaf(t1, c3, di * c4);
            float vv = fmaf(t1, dj * 0.5f, t2);
            vv = fmaf(di * dj, c3, vv);
            const float w_ = fmaf(t2, 0.5f, dj * u);
            const float Cc0 = fmaf(dk0, w_, t3a);
            const float Cc1 = fmaf(dk1, w_, t3b);
            taA[0] = fmaf(d0, Cc0, taA[0]);  taB[0] = fmaf(d0, Cc1, taB[0]);
            taA[1] = fmaf(d1, Cc0, taA[1]);  taB[1] = fmaf(d1, Cc1, taB[1]);
            taA[2] = fmaf(d2, Cc0, taA[2]);  taB[2] = fmaf(d2, Cc1, taB[2]);
            taA[3] = fmaf(d3, Cc0, taA[3]);  taB[3] = fmaf(d3, Cc1, taB[3]);
            taA[4] = fmaf(d4, Cc0, taA[4]);  taB[4] = fmaf(d4, Cc1, taB[4]);
            taA[5] = fmaf(d5, Cc0, taA[5]);  taB[5] = fmaf(d5, Cc1, taB[5]);
            taA[6] = fmaf(d6, Cc0, taA[6]);  taB[6] = fmaf(d6, Cc1, taB[6]);
            taA[7] = fmaf(d7, Cc0, taA[7]);  taB[7] = fmaf(d7, Cc1, taB[7]);
            ts3[0] = fmaf(d0, vv, ts3[0]);
            ts3[1] = fmaf(d1, vv, ts3[1]);
            ts3[2] = fmaf(d2, vv, ts3[2]);
            ts3[3] = fmaf(d3, vv, ts3[3]);
            ts3[4] = fmaf(d4, vv, ts3[4]);
            ts3[5] = fmaf(d5, vv, ts3[5]);
            ts3[6] = fmaf(d6, vv, ts3[6]);
            ts3[7] = fmaf(d7, vv, ts3[7]);
            t3a = fmaf(dk0, vv, t3a);
            t3b = fmaf(dk1, vv, t3b);
            t2 = fmaf(dj, fmaf(di, 0.5f, t1), t2);
            t1 += di;
        }
        // sink all dummy results (keep live, no cost) and pin ordering
        asm volatile("" :: "v"(t1), "v"(t2), "v"(t3a), "v"(t3b),
                     "v"(ts3[0]), "v"(ts3[1]), "v"(ts3[2]), "v"(ts3[3]),
                     "v"(ts3[4]), "v"(ts3[5]), "v"(ts3[6]), "v"(ts3[7]),
                     "v"(taA[0]), "v"(taA[1]), "v"(taA[2]), "v"(taA[3]),
                     "v"(taA[4]), "v"(taA[5]), "v"(taA[6]), "v"(taA[7]) : "memory");
        asm volatile("" :: "v"(taB[0]), "v"(taB[1]), "v"(taB[2]), "v"(taB[3]),
                     "v"(taB[4]), "v"(taB[5]), "v"(taB[6]), "v"(taB[7]) : "memory");
        __builtin_amdgcn_sched_barrier(0);
    }

    // ---------------- Phase A: real chunk scan (LDS-fed) ----------------
    const int seg0 = w * 32;
    const int len = min(32, NSEG - seg0);

    float s1 = 0.f, s2 = 0.f, s3a = 0.f, s3b = 0.f;
    float s3[8];
    float accA[8], accB[8];
#pragma unroll
    for (int k = 0; k < 8; ++k) {
        s3[k] = 0.f;
        accA[k] = 0.f;
        accB[k] = 0.f;
    }

    const float* dbase = lds + seg0 * 8;
#pragma unroll 4
    for (int s = 0; s < len; ++s) {
        const float4 A = *reinterpret_cast<const float4*>(dbase + s * 8);
        const float4 B = *reinterpret_cast<const float4*>(dbase + s * 8 + 4);
        const float d0 = A.x, d1 = A.y, d2 = A.z, d3 = A.w;
        const float d4 = B.x, d5 = B.y, d6 = B.z, d7 = B.w;

        const float di = sel8(d0, d1, d2, d3, d4, d5, d6, d7, ib0, ib1, ib2);
        const float dj = sel8(d0, d1, d2, d3, d4, d5, d6, d7, jb0, jb1, jb2);
        const float xa = kb0 ? d2 : d0, xb = kb0 ? d6 : d4;
        const float dk0 = kb1 ? xb : xa;
        const float ya = kb0 ? d3 : d1, yb = kb0 ? d7 : d5;
        const float dk1 = kb1 ? yb : ya;

        const float u = fmaf(s1, c3, di * c4);    // s1/6 + di/24
        float vv = fmaf(s1, dj * 0.5f, s2);       // s2 + s1*dj/2
        vv = fmaf(di * dj, c3, vv);               // + di*dj/6
        const float w_ = fmaf(s2, 0.5f, dj * u);  // s2/2 + dj*u

        const float Cc0 = fmaf(dk0, w_, s3a);     // uses OLD s3[ka0]
        const float Cc1 = fmaf(dk1, w_, s3b);

        accA[0] = fmaf(d0, Cc0, accA[0]);  accB[0] = fmaf(d0, Cc1, accB[0]);
        accA[1] = fmaf(d1, Cc0, accA[1]);  accB[1] = fmaf(d1, Cc1, accB[1]);
        accA[2] = fmaf(d2, Cc0, accA[2]);  accB[2] = fmaf(d2, Cc1, accB[2]);
        accA[3] = fmaf(d3, Cc0, accA[3]);  accB[3] = fmaf(d3, Cc1, accB[3]);
        accA[4] = fmaf(d4, Cc0, accA[4]);  accB[4] = fmaf(d4, Cc1, accB[4]);
        accA[5] = fmaf(d5, Cc0, accA[5]);  accB[5] = fmaf(d5, Cc1, accB[5]);
        accA[6] = fmaf(d6, Cc0, accA[6]);  accB[6] = fmaf(d6, Cc1, accB[6]);
        accA[7] = fmaf(d7, Cc0, accA[7]);  accB[7] = fmaf(d7, Cc1, accB[7]);
        s3[0] = fmaf(d0, vv, s3[0]);
        s3[1] = fmaf(d1, vv, s3[1]);
        s3[2] = fmaf(d2, vv, s3[2]);
        s3[3] = fmaf(d3, vv, s3[3]);
        s3[4] = fmaf(d4, vv, s3[4]);
        s3[5] = fmaf(d5, vv, s3[5]);
        s3[6] = fmaf(d6, vv, s3[6]);
        s3[7] = fmaf(d7, vv, s3[7]);

        s3a = fmaf(dk0, vv, s3a);
        s3b = fmaf(dk1, vv, s3b);
        s2 = fmaf(dj, fmaf(di, 0.5f, s1), s2);
        s1 += di;
    }

    // write chunk lvl1-3 to LDS slot w; lvl3 layout [t1*65 + t2*8 + t3]
    {
        float* sp = lds + SLOTOFF + w * SLOT;
        if (j == 0) sp[i] = s1;
        sp[8 + i * 8 + j] = s2;
        float* s3p = sp + 72 + i * 65 + j * 8;
#pragma unroll
        for (int k = 0; k < 8; ++k) s3p[k] = s3[k];
    }
    __syncthreads();

    // ---------------- Phase B: exclusive prefix fold (Chen, lvl1-3) ------
    float a1 = 0.f, a2 = 0.f, a3A = 0.f, a3B = 0.f;
    {
        const float* bp = lds + SLOTOFF;
        for (int b = 0; b < w; ++b, bp += SLOT) {
            const float b1i = bp[i], b1j = bp[j];
            const float b1k0 = bp[ka0], b1k1 = bp[ka1];
            const float b2ij = bp[8 + i * 8 + j];
            const float b2jk0 = bp[8 + j * 8 + ka0];
            const float b2jk1 = bp[8 + j * 8 + ka1];
            const float b3a = bp[72 + i * 65 + j * 8 + ka0];
            const float b3b = bp[72 + i * 65 + j * 8 + ka1];
            a3A = fmaf(a2, b1k0, fmaf(a1, b2jk0, a3A + b3a));
            a3B = fmaf(a2, b1k1, fmaf(a1, b2jk1, a3B + b3b));
            a2 = fmaf(a1, b1j, a2 + b2ij);
            a1 += b1i;
        }
    }

    // ---------------- Phase C: contribution -> contrib[w][c*64+lane] -----
    {
        const float* cp = lds + SLOTOFF + w * SLOT;
        float* cb = lds + CONTRIB + w * 1024 + lane;
#pragma unroll
        for (int l = 0; l < 8; ++l) {
            const float b1l = cp[l];
            const float b2a = cp[8 + ka0 * 8 + l];
            const float b2b = cp[8 + ka1 * 8 + l];
            const float b3a = cp[72 + j * 65 + ka0 * 8 + l];
            const float b3b = cp[72 + j * 65 + ka1 * 8 + l];
            const float va = fmaf(a3A, b1l, fmaf(a2, b2a, fmaf(a1, b3a, accA[l])));
            const float vb = fmaf(a3B, b1l, fmaf(a2, b2b, fmaf(a1, b3b, accB[l])));
            cb[l * 64] = va;          // c = 0*8 + l
            cb[(8 + l) * 64] = vb;    // c = 1*8 + l
        }
    }

    // ---------------- final lvl1-3 (wave 15; lvl3 k-slice per block) -----
    if (w == 15) {
        const float* bp = lds + SLOTOFF + 15 * SLOT;
        const float b1i = bp[i], b1j = bp[j];
        const float b1k0 = bp[ka0], b1k1 = bp[ka1];
        const float b2ij = bp[8 + i * 8 + j];
        const float b2jk0 = bp[8 + j * 8 + ka0];
        const float b2jk1 = bp[8 + j * 8 + ka1];
        const float b3a = bp[72 + i * 65 + j * 8 + ka0];
        const float b3b = bp[72 + i * 65 + j * 8 + ka1];
        a3A = fmaf(a2, b1k0, fmaf(a1, b2jk0, a3A + b3a));
        a3B = fmaf(a2, b1k1, fmaf(a1, b2jk1, a3B + b3b));
        a2 = fmaf(a1, b1j, a2 + b2ij);
        a1 += b1i;
        float* o = out + (size_t)n * SIG;
        o[72 + i * 64 + j * 8 + ka0] = a3A;
        o[72 + i * 64 + j * 8 + ka1] = a3B;
        if (kq == 0) {
            o[8 + i * 8 + j] = a2;
            if (j == 0) o[i] = a1;
        }
    }
    __syncthreads();

    // ---------------- reduce over w, transpose, coalesced store ----------
    {
        float s = 0.f;
        const float* c0 = lds + CONTRIB + tid;
#pragma unroll
        for (int ww = 0; ww < 16; ++ww) s += c0[ww * 1024];
        lds[TRANSO + (tid & 63) * 17 + (tid >> 6)] = s;
    }
    __syncthreads();
    if (tid < 256) {
        const int lp = tid >> 2, cq = tid & 3;
        const float* tp = lds + TRANSO + lp * 17 + cq * 4;
        float4 r;
        r.x = tp[0]; r.y = tp[1]; r.z = tp[2]; r.w = tp[3];
        *reinterpret_cast<float4*>(out + (size_t)n * SIG + 584 + lp * 64 + kq * 16 + cq * 4) = r;
    }
}

extern "C" void kernel_launch(void* const* d_in, const int* in_sizes, int n_in,
                              void* d_out, int out_size, void* d_ws, size_t ws_size,
                              hipStream_t stream) {
    const float* path = (const float*)d_in[0];
    float* out = (float*)d_out;
    (void)hipFuncSetAttribute((const void*)sig_diag,
                              hipFuncAttributeMaxDynamicSharedMemorySize,
                              (int)LDS_BYTES);
    // 64 batches x 4 k-quarters = 256 blocks (1 per CU), 1024 threads each
    sig_diag<<<256, 1024, LDS_BYTES, stream>>>(path, out);
}